// Round 8
// baseline (19726.717 us; speedup 1.0000x reference)
//
#include <hip/hip_runtime.h>

// Persistent batched-GRU kernel for MI355X (gfx950), round 8.
// B=16384, T=1024, H=256. 256 blocks x 1024 threads (16 waves, 1 block/CU).
// Round-8 = round-7 phase-shifted half-problem pipeline + ONE fix:
//   gates_half for sub-problem B must read x rows 32..63 of the slot
//   (round 7 read rows 0..31 -> B evolved with A's x; absmax 2.9e-2).
// Pipeline: rows 0-31 = A, rows 32-63 = B, independent h-state.
//   P1: MFMA_A(t) || gates_B(t-1)   (data-independent -> dual-pipe overlap)
//   P2: MFMA_B(t) || gates_A(t)
// Each barrier region has MFMA+VMEM work AND gate VALU work concurrently.
// Carried: lgkm-only barriers (weight prefetch stays in flight across them),
// parity-ring b-frags (no mov chains), anchored imm13 weight addressing,
// module-global L2-cached weights, rcp-sigmoid, DPP out-reduce (lane 15),
// transposed x_buf, chunked x/out staging. No sigma-swizzle (raised conflicts).

#define B_TOTAL 16384
#define T_LEN   1024
#define M_ROWS  64
#define M_HALF  32
#define NBLOCKS (B_TOTAL / M_ROWS)      // 256 -> 1 block/CU
#define NTHREADS 1024                   // 16 waves
#define LDSW    264                     // h row stride in shorts
#define TCH     32                      // t-chunk length
#define NCH     (T_LEN / TCH)
#define XSTR    68                      // x_buf t-row stride (floats)
#define OSTR    37                      // out_buf row stride (floats)

typedef short short8 __attribute__((ext_vector_type(8)));
typedef float f32x4  __attribute__((ext_vector_type(4)));

__device__ unsigned short g_wsw[196608];   // swizzled bf16 W_hh (384 KB, L2-cacheable)

__device__ __forceinline__ unsigned short f2b(float f) {
  unsigned u = __builtin_bit_cast(unsigned, f);
  u += 0x7fffu + ((u >> 16) & 1u);
  return (unsigned short)(u >> 16);
}
__device__ __forceinline__ float fast_sig(float x) {
  return __builtin_amdgcn_rcpf(1.0f + __expf(-x));   // v_exp + v_rcp
}
__device__ __forceinline__ float fast_tanh(float x) {
  return 2.0f * fast_sig(2.0f * x) - 1.0f;
}
// sum over a 16-lane DPP row; result valid in the LAST lane (r16==15)
__device__ __forceinline__ float dpp_red16(float v) {
  int x = __builtin_bit_cast(int, v);
  v += __builtin_bit_cast(float, __builtin_amdgcn_update_dpp(0, x, 0x118, 0xF, 0xF, true)); // row_shr:8
  x = __builtin_bit_cast(int, v);
  v += __builtin_bit_cast(float, __builtin_amdgcn_update_dpp(0, x, 0x114, 0xF, 0xF, true)); // row_shr:4
  x = __builtin_bit_cast(int, v);
  v += __builtin_bit_cast(float, __builtin_amdgcn_update_dpp(0, x, 0x112, 0xF, 0xF, true)); // row_shr:2
  x = __builtin_bit_cast(int, v);
  v += __builtin_bit_cast(float, __builtin_amdgcn_update_dpp(0, x, 0x111, 0xF, 0xF, true)); // row_shr:1
  return v;
}
// barrier draining LDS only (weight prefetch vmem loads stay in flight)
__device__ __forceinline__ void barrier_lgkm() {
  asm volatile("s_waitcnt lgkmcnt(0)\n\ts_barrier" ::: "memory");
}

// Swizzle W_hh (768x256 f32 row-major) into fragment-major bf16:
// dst[((nt*8 + ks)*64 + lane)*8 + e] = bf16(W[nt*16 + (lane&15)][ks*32 + (lane>>4)*8 + e])
__global__ void prep_w(const float* __restrict__ w_hh) {
  int tid  = blockIdx.x * 256 + threadIdx.x;     // 196608 total
  int e    = tid & 7;
  int lane = (tid >> 3) & 63;
  int ks   = (tid >> 9) & 7;
  int nt   = tid >> 12;
  int row  = nt * 16 + (lane & 15);
  int col  = ks * 32 + (lane >> 4) * 8 + e;
  g_wsw[tid] = f2b(w_hh[row * 256 + col]);
}

// b-frag load: anchored so (ks*512-1792)*2B spans [-3584,+3584] (signed imm13)
#define BLD(g, ks) (*(const short8*)(bp[g] + ((ks) * 512 - 1792)))

__global__ __launch_bounds__(NTHREADS, 4) void gru_kernel(
    const float* __restrict__ x,
    const float* __restrict__ w_ih,
    const float* __restrict__ b_ih,
    const float* __restrict__ b_hh,
    const float* __restrict__ w_out,
    const float* __restrict__ b_out,
    float* __restrict__ out)
{
  __shared__ unsigned short hA[M_HALF * LDSW];   // 16.9 KB, sub-problem A state
  __shared__ unsigned short hB[M_HALF * LDSW];   // 16.9 KB, sub-problem B state
  __shared__ float x_buf[2][TCH * XSTR];         // [t][row], double-buffered chunks
  __shared__ float out_buf[2][M_ROWS * OSTR];    // [row][t]
  __shared__ float opA[16][M_HALF];              // per-wave out partials
  __shared__ float opB[16][M_HALF];

  const int tid  = threadIdx.x;
  const int w    = tid >> 6;        // wave 0..15
  const int lane = tid & 63;
  const int r16  = lane & 15;
  const int q    = lane >> 4;
  const long base = (long)blockIdx.x * M_ROWS;

  for (int i = tid; i < M_HALF * LDSW; i += NTHREADS) { hA[i] = 0; hB[i] = 0; }

  const int c = w * 16 + r16;       // this wave's matched column
  const float wi_r  = w_ih[c];
  const float wi_z  = w_ih[256 + c];
  const float wi_n  = w_ih[512 + c];
  const float bt_r  = b_ih[c]       + b_hh[c];
  const float bt_z  = b_ih[256 + c] + b_hh[256 + c];
  const float bih_n = b_ih[512 + c];
  const float bhh_n = b_hh[512 + c];
  const float wo    = w_out[c];
  const float bo    = b_out[0];
  const f32x4 zero4 = {0.f, 0.f, 0.f, 0.f};

  f32x4 h_regA[2], h_regB[2];       // C layout: row = mt*16 + q*4 + i, col = c
#pragma unroll
  for (int mt = 0; mt < 2; ++mt) { h_regA[mt] = zero4; h_regB[mt] = zero4; }
  f32x4 accA[2][3], accB[2][3];     // pipeline accumulators (live across phases)

  const unsigned short* bp[3];
#pragma unroll
  for (int g = 0; g < 3; ++g)
    bp[g] = g_wsw + ((long)((g * 16 + w) * 8) * 64 + lane) * 8 + 1792;

  const int row64 = tid >> 4;            // 0..63 (refill/flush role)
  const int ko2   = (tid & 15) * 2;      // t-pair within chunk

  // prefill x chunk 0 (transposed into x_buf[0])
  {
    float2 v = *(const float2*)&x[(base + row64) * T_LEN + ko2];
    x_buf[0][(ko2 + 0) * XSTR + row64] = v.x;
    x_buf[0][(ko2 + 1) * XSTR + row64] = v.y;
  }

  // parity ring: bf0 even-ks frags, bf1 odd-ks. Initial fill ks=0,1.
  short8 bf0[3], bf1[3];
#pragma unroll
  for (int g = 0; g < 3; ++g) { bf0[g] = BLD(g, 0); bf1[g] = BLD(g, 1); }

  barrier_lgkm();

  // gh half-matmul: acc = h_src(32 rows) @ W^T for this wave's 3 gate cols
  auto mfma_half = [&](const unsigned short* hs, f32x4 (&acc)[2][3]) {
#pragma unroll
    for (int mt = 0; mt < 2; ++mt)
#pragma unroll
      for (int g = 0; g < 3; ++g) acc[mt][g] = zero4;
    const unsigned short* ar = hs + r16 * LDSW + q * 8;
#pragma unroll
    for (int ks = 0; ks < 8; ++ks) {
      short8 a[2];
#pragma unroll
      for (int mt = 0; mt < 2; ++mt)
        a[mt] = *(const short8*)(ar + mt * (16 * LDSW) + ks * 32);
      if ((ks & 1) == 0) {
#pragma unroll
        for (int g = 0; g < 3; ++g)
#pragma unroll
          for (int mt = 0; mt < 2; ++mt)
            acc[mt][g] = __builtin_amdgcn_mfma_f32_16x16x32_bf16(a[mt], bf0[g], acc[mt][g], 0, 0, 0);
        if (ks < 6) {
#pragma unroll
          for (int g = 0; g < 3; ++g) bf0[g] = BLD(g, ks + 2);
        }
      } else {
#pragma unroll
        for (int g = 0; g < 3; ++g)
#pragma unroll
          for (int mt = 0; mt < 2; ++mt)
            acc[mt][g] = __builtin_amdgcn_mfma_f32_16x16x32_bf16(a[mt], bf1[g], acc[mt][g], 0, 0, 0);
        if (ks < 6) {
#pragma unroll
          for (int g = 0; g < 3; ++g) bf1[g] = BLD(g, ks + 2);
        }
      }
    }
    // prefetch next phase's ks=0/1 (weights step-invariant); stays in flight
    // through the gate VALU and the lgkm-only barrier.
#pragma unroll
    for (int g = 0; g < 3; ++g) { bf0[g] = BLD(g, 0); bf1[g] = BLD(g, 1); }
  };

  // gates for one half-problem; xrow must ALREADY point at this half's rows
  // (A: slot base + 0, B: slot base + M_HALF).
  auto gates_half = [&](f32x4 (&acc)[2][3], f32x4 (&h_reg)[2],
                        unsigned short* hd, const float* xrow,
                        float (*op)[M_HALF]) {
#pragma unroll
    for (int mt = 0; mt < 2; ++mt) {
      f32x4 xv = *(const f32x4*)&xrow[mt * 16 + q * 4];   // broadcast b128
      f32x4 vo;
#pragma unroll
      for (int i = 0; i < 4; ++i) {
        float rg = fast_sig(acc[mt][0][i] + xv[i] * wi_r + bt_r);
        float zg = fast_sig(acc[mt][1][i] + xv[i] * wi_z + bt_z);
        float ng = fast_tanh(xv[i] * wi_n + bih_n + rg * (acc[mt][2][i] + bhh_n));
        float hn = (1.0f - zg) * ng + zg * h_reg[mt][i];
        h_reg[mt][i] = hn;
        hd[(mt * 16 + q * 4 + i) * LDSW + c] = f2b(hn);
        vo[i] = fmaxf(hn, 0.0f) * wo;
      }
#pragma unroll
      for (int i = 0; i < 4; ++i) vo[i] = dpp_red16(vo[i]);
      if (r16 == 15) {
#pragma unroll
        for (int i = 0; i < 4; ++i)
          op[w][mt * 16 + q * 4 + i] = vo[i];
      }
    }
  };

#pragma unroll 1
  for (int t = 0; t < T_LEN; ++t) {
    const int tr = t & (TCH - 1);
    const int tc = t >> 5;
    const int xp = tc & 1;
    const int ob = tc & 1;
    const int obP = (tr == 0) ? (ob ^ 1) : ob;        // buffer holding slot t-1
    const int sP  = (tr == 0) ? (TCH - 1) : (tr - 1); // slot of t-1

    // ================= P1: MFMA_A(t) || gates_B(t-1) =================
    if (t > 0 && tid < M_HALF) {      // finalize out_A(t-1) (opA from P2(t-1))
      float o = bo;
#pragma unroll
      for (int ww = 0; ww < 16; ++ww) o += opA[ww][tid];
      out_buf[obP][tid * OSTR + sP] = o;
    }
    mfma_half(hA, accA);
    if (t > 0) {
      const float* xB = (tr == 0) ? &x_buf[xp ^ 1][(TCH - 1) * XSTR]
                                  : &x_buf[xp][(tr - 1) * XSTR];
      gates_half(accB, h_regB, hB, xB + M_HALF, opB);   // B = rows 32..63 (r7 fix)
    }
    if (tr == 1) {
      if (tc + 1 < NCH) {             // refill next x chunk
        float2 v = *(const float2*)&x[(base + row64) * T_LEN + (tc + 1) * TCH + ko2];
        x_buf[xp ^ 1][(ko2 + 0) * XSTR + row64] = v.x;
        x_buf[xp ^ 1][(ko2 + 1) * XSTR + row64] = v.y;
      }
      if (tc > 0) {                   // flush completed chunk tc-1
        float2 v;
        v.x = out_buf[ob ^ 1][row64 * OSTR + ko2];
        v.y = out_buf[ob ^ 1][row64 * OSTR + ko2 + 1];
        *(float2*)&out[(base + row64) * T_LEN + (tc - 1) * TCH + ko2] = v;
      }
    }
    barrier_lgkm();

    // ================= P2: MFMA_B(t) || gates_A(t) =================
    if (t > 0 && tid < M_HALF) {      // finalize out_B(t-1) (opB from P1)
      float o = bo;
#pragma unroll
      for (int ww = 0; ww < 16; ++ww) o += opB[ww][tid];
      out_buf[obP][(M_HALF + tid) * OSTR + sP] = o;
    }
    mfma_half(hB, accB);
    gates_half(accA, h_regA, hA, &x_buf[xp][tr * XSTR], opA);  // A = rows 0..31
    barrier_lgkm();
  }

  // ===== epilogue: drain the one-phase B lag and finalize step T-1 =====
  if (tid < M_HALF) {                 // finalize out_A(T-1)
    float o = bo;
#pragma unroll
    for (int ww = 0; ww < 16; ++ww) o += opA[ww][tid];
    out_buf[(NCH - 1) & 1][tid * OSTR + (TCH - 1)] = o;
  }
  gates_half(accB, h_regB, hB,
             &x_buf[(NCH - 1) & 1][(TCH - 1) * XSTR] + M_HALF, opB);  // B rows
  barrier_lgkm();
  if (tid < M_HALF) {                 // finalize out_B(T-1)
    float o = bo;
#pragma unroll
    for (int ww = 0; ww < 16; ++ww) o += opB[ww][tid];
    out_buf[(NCH - 1) & 1][(M_HALF + tid) * OSTR + (TCH - 1)] = o;
  }
  barrier_lgkm();
  {  // flush final chunk
    float2 v;
    v.x = out_buf[(NCH - 1) & 1][row64 * OSTR + ko2];
    v.y = out_buf[(NCH - 1) & 1][row64 * OSTR + ko2 + 1];
    *(float2*)&out[(base + row64) * T_LEN + (NCH - 1) * TCH + ko2] = v;
  }
}

extern "C" void kernel_launch(void* const* d_in, const int* in_sizes, int n_in,
                              void* d_out, int out_size, void* d_ws, size_t ws_size,
                              hipStream_t stream) {
  const float* x     = (const float*)d_in[0];
  const float* w_ih  = (const float*)d_in[1];
  const float* w_hh  = (const float*)d_in[2];
  const float* b_ih  = (const float*)d_in[3];
  const float* b_hh  = (const float*)d_in[4];
  const float* w_out = (const float*)d_in[5];
  const float* b_out = (const float*)d_in[6];
  float* out = (float*)d_out;

  prep_w<<<768, 256, 0, stream>>>(w_hh);
  gru_kernel<<<NBLOCKS, NTHREADS, 0, stream>>>(x, w_ih, b_ih, b_hh, w_out, b_out, out);
}

// Round 9
// 9359.581 us; speedup vs baseline: 2.1076x; 2.1076x over previous
//
#include <hip/hip_runtime.h>

// Persistent batched-GRU kernel for MI355X (gfx950), round 9.
// B=16384, T=1024, H=256. Round-9: WEIGHTS FULLY REGISTER-RESIDENT.
// Diagnosis r4-r8: per-step weight-fragment loads from L2 (384-768 KB/CU/step,
// working set >> L1) are the serializing resource; every structure that added
// loads or barriers regressed. Fix: hold all of W_hh in VGPRs.
//   1024 blocks x 512 threads (8 waves). Each block owns 16 batch rows for
//   all 1024 steps; each wave owns 32 matched columns c=w*32+j*16+r16
//   (j=0,1) x 3 gates = 48 bf16 fragments = 192 VGPR, loaded ONCE.
//   2 waves/SIMD (launch_bounds(512,2) -> 256 VGPR/wave). K-loop is pure
//   LDS(A) + MFMA; zero global traffic in steady state.
// Carried: h double-buffer + one lgkm-only barrier/step, rcp-sigmoid,
// DPP out-reduce (lane 15), transposed x chunks, staged out chunks.

#define B_TOTAL 16384
#define T_LEN   1024
#define M_ROWS  16
#define NBLOCKS (B_TOTAL / M_ROWS)      // 1024 blocks; ~4 sequential per CU
#define NTHREADS 512                    // 8 waves
#define LDSW    264                     // h row stride in shorts
#define TCH     32                      // t-chunk length
#define NCH     (T_LEN / TCH)           // 32
#define XSTR    20                      // x_buf t-row stride (floats, 16 rows + pad)
#define OSTR    33                      // out_buf row stride (floats)

typedef short short8 __attribute__((ext_vector_type(8)));
typedef float f32x4  __attribute__((ext_vector_type(4)));

__device__ unsigned short g_wsw[196608];   // swizzled bf16 W_hh (384 KB)

__device__ __forceinline__ unsigned short f2b(float f) {
  unsigned u = __builtin_bit_cast(unsigned, f);
  u += 0x7fffu + ((u >> 16) & 1u);
  return (unsigned short)(u >> 16);
}
__device__ __forceinline__ float fast_sig(float x) {
  return __builtin_amdgcn_rcpf(1.0f + __expf(-x));
}
__device__ __forceinline__ float fast_tanh(float x) {
  return 2.0f * fast_sig(2.0f * x) - 1.0f;
}
// sum over a 16-lane DPP row; result valid in the LAST lane (r16==15)
__device__ __forceinline__ float dpp_red16(float v) {
  int x = __builtin_bit_cast(int, v);
  v += __builtin_bit_cast(float, __builtin_amdgcn_update_dpp(0, x, 0x118, 0xF, 0xF, true)); // row_shr:8
  x = __builtin_bit_cast(int, v);
  v += __builtin_bit_cast(float, __builtin_amdgcn_update_dpp(0, x, 0x114, 0xF, 0xF, true)); // row_shr:4
  x = __builtin_bit_cast(int, v);
  v += __builtin_bit_cast(float, __builtin_amdgcn_update_dpp(0, x, 0x112, 0xF, 0xF, true)); // row_shr:2
  x = __builtin_bit_cast(int, v);
  v += __builtin_bit_cast(float, __builtin_amdgcn_update_dpp(0, x, 0x111, 0xF, 0xF, true)); // row_shr:1
  return v;
}
// barrier draining LDS only (no vmcnt(0): global stores stay in flight)
__device__ __forceinline__ void barrier_lgkm() {
  asm volatile("s_waitcnt lgkmcnt(0)\n\ts_barrier" ::: "memory");
}

// Swizzle W_hh (768x256 f32 row-major) into fragment-major bf16:
// dst[((nt*8 + ks)*64 + lane)*8 + e] = bf16(W[nt*16 + (lane&15)][ks*32 + (lane>>4)*8 + e])
__global__ void prep_w(const float* __restrict__ w_hh) {
  int tid  = blockIdx.x * 256 + threadIdx.x;     // 196608 total
  int e    = tid & 7;
  int lane = (tid >> 3) & 63;
  int ks   = (tid >> 9) & 7;
  int nt   = tid >> 12;
  int row  = nt * 16 + (lane & 15);
  int col  = ks * 32 + (lane >> 4) * 8 + e;
  g_wsw[tid] = f2b(w_hh[row * 256 + col]);
}

__global__ __launch_bounds__(NTHREADS, 2) void gru_kernel(
    const float* __restrict__ x,
    const float* __restrict__ w_ih,
    const float* __restrict__ b_ih,
    const float* __restrict__ b_hh,
    const float* __restrict__ w_out,
    const float* __restrict__ b_out,
    float* __restrict__ out)
{
  __shared__ unsigned short h_lds[2][M_ROWS * LDSW];  // 2 x 8.25 KB
  __shared__ float x_buf[2][TCH * XSTR];              // 2 x 2.5 KB, [t][row]
  __shared__ float out_buf[2][M_ROWS * OSTR];         // 2 x 2.06 KB, [row][t]
  __shared__ float op[2][8][M_ROWS];                  // 2 x 0.5 KB

  const int tid  = threadIdx.x;
  const int w    = tid >> 6;        // wave 0..7
  const int lane = tid & 63;
  const int r16  = lane & 15;
  const int q    = lane >> 4;
  const long base = (long)blockIdx.x * M_ROWS;

  for (int i = tid; i < M_ROWS * LDSW; i += NTHREADS) h_lds[0][i] = 0;  // h0 = 0

  // ---- resident weights: 48 frags (3 gates x 2 col-tiles x 8 k-steps) ----
  // frag (g,j,ks) at ((g*16 + w*2 + j)*8 + ks)*512 + lane*8
  short8 wr[3][2][8];
#pragma unroll
  for (int g = 0; g < 3; ++g)
#pragma unroll
    for (int j = 0; j < 2; ++j)
#pragma unroll
      for (int ks = 0; ks < 8; ++ks)
        wr[g][j][ks] = *(const short8*)&g_wsw[(((g * 16 + w * 2 + j) * 8 + ks) * 64 + lane) * 8];

  // per-lane constants for cols c(j) = w*32 + j*16 + r16
  float wi_r[2], wi_z[2], wi_n[2], bt_r[2], bt_z[2], bih_n[2], bhh_n[2], wo[2];
  int cc[2];
#pragma unroll
  for (int j = 0; j < 2; ++j) {
    int c = w * 32 + j * 16 + r16;
    cc[j]    = c;
    wi_r[j]  = w_ih[c];
    wi_z[j]  = w_ih[256 + c];
    wi_n[j]  = w_ih[512 + c];
    bt_r[j]  = b_ih[c]       + b_hh[c];
    bt_z[j]  = b_ih[256 + c] + b_hh[256 + c];
    bih_n[j] = b_ih[512 + c];
    bhh_n[j] = b_hh[512 + c];
    wo[j]    = w_out[c];
  }
  const float bo = b_out[0];
  const f32x4 zero4 = {0.f, 0.f, 0.f, 0.f};

  f32x4 h_reg[2];                   // C layout: row = q*4 + i, col = cc[j]
#pragma unroll
  for (int j = 0; j < 2; ++j) h_reg[j] = zero4;

  const int xr = tid >> 5;          // 0..15: staging row
  const int xt = tid & 31;          // 0..31: staging t-slot

  // prefill x chunk 0 (transposed [t][row])
  x_buf[0][xt * XSTR + xr] = x[(base + xr) * T_LEN + xt];

  barrier_lgkm();

#pragma unroll 1
  for (int t = 0; t < T_LEN; ++t) {
    const int tr = t & (TCH - 1);
    const int tc = t >> 5;
    const int xp = tc & 1;
    const int rp = t & 1;

    // ---- finalize out(t-1): op[(t-1)&1] stable since last barrier ----
    if (t > 0 && tid < M_ROWS) {
      float o = bo;
#pragma unroll
      for (int ww = 0; ww < 8; ++ww) o += op[(t - 1) & 1][ww][tid];
      out_buf[((t - 1) >> 5) & 1][tid * OSTR + ((t - 1) & 31)] = o;
    }

    // ---- K-loop: pure LDS + MFMA (weights in registers) ----
    f32x4 acc[3][2];
#pragma unroll
    for (int g = 0; g < 3; ++g)
#pragma unroll
      for (int j = 0; j < 2; ++j) acc[g][j] = zero4;

    const unsigned short* ar = &h_lds[rp][r16 * LDSW + q * 8];
#pragma unroll
    for (int ks = 0; ks < 8; ++ks) {
      short8 a = *(const short8*)(ar + ks * 32);
#pragma unroll
      for (int g = 0; g < 3; ++g)
#pragma unroll
        for (int j = 0; j < 2; ++j)
          acc[g][j] = __builtin_amdgcn_mfma_f32_16x16x32_bf16(a, wr[g][j][ks], acc[g][j], 0, 0, 0);
    }

    // ---- gates + h publish + out partial ----
    f32x4 xv = *(const f32x4*)&x_buf[xp][tr * XSTR + q * 4];   // broadcast b128
    f32x4 vo = zero4;
    unsigned short* hw = &h_lds[rp ^ 1][0];
#pragma unroll
    for (int j = 0; j < 2; ++j) {
#pragma unroll
      for (int i = 0; i < 4; ++i) {
        float rg = fast_sig(acc[0][j][i] + xv[i] * wi_r[j] + bt_r[j]);
        float zg = fast_sig(acc[1][j][i] + xv[i] * wi_z[j] + bt_z[j]);
        float ng = fast_tanh(xv[i] * wi_n[j] + bih_n[j] + rg * (acc[2][j][i] + bhh_n[j]));
        float hn = (1.0f - zg) * ng + zg * h_reg[j][i];
        h_reg[j][i] = hn;
        hw[(q * 4 + i) * LDSW + cc[j]] = f2b(hn);
        vo[i] += fmaxf(hn, 0.0f) * wo[j];
      }
    }
#pragma unroll
    for (int i = 0; i < 4; ++i) vo[i] = dpp_red16(vo[i]);
    if (r16 == 15) {
#pragma unroll
      for (int i = 0; i < 4; ++i) op[t & 1][w][q * 4 + i] = vo[i];
    }

    // ---- chunk refill/flush (once per 32 steps, at tr==1) ----
    if (tr == 1) {
      if (tc + 1 < NCH)
        x_buf[xp ^ 1][xt * XSTR + xr] = x[(base + xr) * T_LEN + (tc + 1) * TCH + xt];
      if (tc > 0)
        out[(base + xr) * T_LEN + (tc - 1) * TCH + xt] =
            out_buf[(tc - 1) & 1][xr * OSTR + xt];
    }

    barrier_lgkm();
  }

  // ---- epilogue: finalize step T-1, flush last chunk ----
  if (tid < M_ROWS) {
    float o = bo;
#pragma unroll
    for (int ww = 0; ww < 8; ++ww) o += op[(T_LEN - 1) & 1][ww][tid];
    out_buf[((T_LEN - 1) >> 5) & 1][tid * OSTR + (TCH - 1)] = o;
  }
  barrier_lgkm();
  out[(base + xr) * T_LEN + (NCH - 1) * TCH + xt] =
      out_buf[(NCH - 1) & 1][xr * OSTR + xt];
}

extern "C" void kernel_launch(void* const* d_in, const int* in_sizes, int n_in,
                              void* d_out, int out_size, void* d_ws, size_t ws_size,
                              hipStream_t stream) {
  const float* x     = (const float*)d_in[0];
  const float* w_ih  = (const float*)d_in[1];
  const float* w_hh  = (const float*)d_in[2];
  const float* b_ih  = (const float*)d_in[3];
  const float* b_hh  = (const float*)d_in[4];
  const float* w_out = (const float*)d_in[5];
  const float* b_out = (const float*)d_in[6];
  float* out = (float*)d_out;

  prep_w<<<768, 256, 0, stream>>>(w_hh);
  gru_kernel<<<NBLOCKS, NTHREADS, 0, stream>>>(x, w_ih, b_ih, b_hh, w_out, b_out, out);
}